// Round 14
// baseline (458.113 us; speedup 1.0000x reference)
//
#include <hip/hip_runtime.h>

typedef unsigned short u16;
typedef unsigned int   u32;
typedef unsigned long long u64;
typedef __bf16 bf16x8 __attribute__((ext_vector_type(8)));
typedef float  f32x4  __attribute__((ext_vector_type(4)));

#define AS1 __attribute__((address_space(1)))
#define AS3 __attribute__((address_space(3)))

#define M_TOK 8192
#define K_DIM 4096
#define N_DIM 4096
#define BK    32
#define NKT   (K_DIM / BK)   // 128

static __device__ __forceinline__ u16 f2bf(float f) {
  u32 u = __builtin_bit_cast(u32, f);
  return (u16)((u + (0x7FFFu + ((u >> 16) & 1u))) >> 16);
}

// global -> LDS direct copy, 16B per lane. LDS dest is wave-uniform base;
// HW stores lane l at dest + l*16 (linear, rule #21).
static __device__ __forceinline__ void gld_lds16(const void* g, void* l) {
  __builtin_amdgcn_global_load_lds((AS1 u32*)(u64)g, (AS3 u32*)(u32)(u64)l, 16, 0, 0);
}

// ---- fused prep: blocks [0, M_TOK) do per-token x->bf16 + LoRA mid;
//      blocks [M_TOK, M_TOK+2048) convert W_main f32->bf16 (grid-stride). ----
__global__ __launch_bounds__(256) void k_prep(const float* __restrict__ x,
                                              const float* __restrict__ WA,
                                              const float* __restrict__ W,
                                              u16* __restrict__ xb,
                                              float* __restrict__ mid,
                                              u16* __restrict__ Wb) {
  const int t = threadIdx.x;
  if (blockIdx.x >= M_TOK) {
    const int cb = blockIdx.x - M_TOK;           // 0..2047
    const float4* W4 = (const float4*)W;
    ushort4* Wb4 = (ushort4*)Wb;
    const int n4 = (N_DIM * K_DIM) / 4;
    int i = cb * 256 + t;
    for (; i < n4; i += 2048 * 256) {
      float4 v = W4[i];
      ushort4 o;
      o.x = f2bf(v.x); o.y = f2bf(v.y); o.z = f2bf(v.z); o.w = f2bf(v.w);
      Wb4[i] = o;
    }
    return;
  }
  const int m = blockIdx.x;
  const float4* xr = (const float4*)(x + (size_t)m * K_DIM);
  ushort4* xbr = (ushort4*)(xb + (size_t)m * K_DIM);
  float a[8] = {0.f,0.f,0.f,0.f,0.f,0.f,0.f,0.f};
  #pragma unroll
  for (int i = 0; i < 4; ++i) {
    const int k4 = t + i * 256;
    float4 v = xr[k4];
    ushort4 o;
    o.x = f2bf(v.x); o.y = f2bf(v.y); o.z = f2bf(v.z); o.w = f2bf(v.w);
    xbr[k4] = o;
    #pragma unroll
    for (int r = 0; r < 8; ++r) {
      float4 wv = ((const float4*)(WA + (size_t)r * K_DIM))[k4];
      a[r] += v.x * wv.x + v.y * wv.y + v.z * wv.z + v.w * wv.w;
    }
  }
  #pragma unroll
  for (int r = 0; r < 8; ++r) {
    #pragma unroll
    for (int off = 32; off > 0; off >>= 1)
      a[r] += __shfl_down(a[r], off);
  }
  __shared__ float red[4][8];
  const int w = t >> 6, l = t & 63;
  if (l == 0) {
    #pragma unroll
    for (int r = 0; r < 8; ++r) red[w][r] = a[r];
  }
  __syncthreads();
  if (t < 8)
    mid[(size_t)m * 8 + t] = 2.0f * (red[0][t] + red[1][t] + red[2][t] + red[3][t]);
}

// ---- main GEMM: 256x256 tile, BK=32, 8 waves (2Mx4N), A-only 4-deep LDS
// ring (64 KiB), B DIRECT GLOBAL->REGISTER (2 tiles ahead).
// R14: cut the LDS burst in half.  Corrected arithmetic (rule #15): MFMA
//   wall = 64x19.4 = 1242 cyc/SIMD; LDS wall (A+B) = 96 b128 = ~1150
//   cyc/CU (shared pipe).  Five schedules all measured ~their SUM.  B's
//   fragment is contiguous 16B in global B^T (row=n-col, k-run) -> load it
//   straight to regs (L2-resident, ~21 B/cyc/CU demand << 56 L2 share),
//   2 tiles ahead into parity sets bfA/bfB; loads sit AFTER the MFMA
//   cluster that consumes the target set (in-order issue => WAR-safe).
//   LDS now stages A only: 64KB/tile = ~770 cyc < 1242 -> memory phase
//   fits under compute even if partially serialized.  Keeps R8's
//   af-rotation read-ahead (af(kt+1) loaded in dead reg slots mid-tile).
//
// Mixed-FIFO ledger (per wave: 2 gld_lds stage + 4 global B per tile,
// order enforced by sched_barrier(0) fences):
//   per tile kt issues: S(kt+3) [2] at top; ...; B(kt+2) [4] after MFMA.
//   end-of-kt: retire through B(kt+1)  ->  vmcnt(6) = S(kt+3)+B(kt+2).
//     This retires S(kt+2) (older than B(kt+1)) => af-read-ahead of kt+2
//     during kt+1 is legal, and B(kt+1) regs are ready for kt+1.
//   Prologue: S0,S1,S2 then bfA=B(0),bfB=B(1): vmcnt(4) retires
//     S0,S1,S2,B0 (leaves B1) -> tile0 + read-ahead(1) + bfA all legal.
//   Tail: end-125 vmcnt(4) (B(127) left), end-126 vmcnt(0), 127 none.
//   Stage overwrite: S(kt+3) hits buf[kt-1], last read mid-(kt-1) -> one
//   barrier ago -> safe (R8 invariant).
__global__ __launch_bounds__(512, 2) void k_gemm(
    const u16* __restrict__ A, const u16* __restrict__ B,
    const float* __restrict__ bias, const int* __restrict__ mask,
    const float* __restrict__ mid, const float* __restrict__ WBw,
    float* __restrict__ out) {
  __shared__ u16 smem[4][256][BK];   // A-only ring: 4 bufs x 16KB = 64 KiB

  const int t = threadIdx.x;
  const int wid = t >> 6, l = t & 63;
  const int wr = wid >> 2, wc = wid & 3;   // 2x4 wave grid -> 128x64 out/wave
  const int fr = l & 15, fq = l >> 4;

  // T1: XCD-aware swizzle (512 blocks, 512%8==0 -> bijective)
  const int bid = blockIdx.x;
  const int swz = (bid & 7) * 64 + (bid >> 3);
  const int bm = swz >> 4, bn = swz & 15;

  const char* Ag = (const char*)(A + (size_t)bm * 256 * K_DIM);
  const char* Bg = (const char*)(B + (size_t)bn * 256 * K_DIM);
  const size_t rowb = (size_t)K_DIM * 2;

  // A staging: 512 thr x 16B = 8KB per gld_lds; two per tile (row halves).
  // thread t covers row t>>2; source 16B chunk is the T2 pre-swizzle
  // (t&3)^((t>>3)&3) (4-lane groups stay within one 64B row-segment).
  const int srow = t >> 2;
  const int schk = (((t & 3) ^ ((t >> 3) & 3)) * 16);
  const char* gA0 = Ag + (size_t)srow * rowb + schk;
  const char* gA1 = Ag + (size_t)(128 + srow) * rowb + schk;
  char* lbase = (char*)&smem[0][0][0] + wid * 1024;

  // B direct: lane address for frag n = Bg + (wc*64+n*16+fr)*rowb + fq*16.
  const char* qB = Bg + (size_t)(wc * 64 + fr) * rowb + fq * 16;

  f32x4 acc[8][4];
  #pragma unroll
  for (int m = 0; m < 8; ++m)
    #pragma unroll
    for (int n = 0; n < 4; ++n)
      acc[m][n] = (f32x4){0.f, 0.f, 0.f, 0.f};

  // loop-carried regs: af rotating, bfA/bfB parity B-sets (16 b128 live)
  bf16x8 af[8], bfA[4], bfB[4];

  // prologue: stage A tiles 0..2 -> bufs 0..2 (6 ops, ordered)
  #pragma unroll
  for (int pk = 0; pk < 3; ++pk) {
    gld_lds16(gA0 + pk * 64, lbase + pk * 16384);
    gld_lds16(gA1 + pk * 64, lbase + pk * 16384 + 8192);
  }
  __builtin_amdgcn_sched_barrier(0);
  // B(0) -> bfA, B(1) -> bfB (8 ops, ordered after stages)
  #pragma unroll
  for (int n = 0; n < 4; ++n)
    bfA[n] = *(const bf16x8*)(qB + (size_t)n * 16 * rowb);
  __builtin_amdgcn_sched_barrier(0);
  #pragma unroll
  for (int n = 0; n < 4; ++n)
    bfB[n] = *(const bf16x8*)(qB + (size_t)n * 16 * rowb + 64);
  __builtin_amdgcn_sched_barrier(0);
  asm volatile("s_waitcnt vmcnt(4)" ::: "memory");   // retire S0,S1,S2,B0
  __builtin_amdgcn_s_barrier();

  // T2 read-side swizzled column (u16 units), wave-invariant
  const int csw = (fq ^ ((fr >> 1) & 3)) * 8;

  // preload af(0) from buf 0
  {
    const u16* Ap_ = &smem[0][wr * 128 + fr][csw];
    #pragma unroll
    for (int m = 0; m < 8; ++m) af[m] = *(const bf16x8*)(Ap_ + m * 16 * BK);
  }

  // running pointers, pre-offset: stage tile kt+3 (gA at +192), B tile
  // kt+2 (qB at +128); both advance 256 per 4-tile group.
  const char* pA0 = gA0 + 192;
  const char* pA1 = gA1 + 192;
  const char* pB  = qB + 128;

  // One K32-tile.  RBUF: LDS buf of kt+1 (af read-ahead).  SB: stage buf.
  // BFC: this tile's B set (also reload target for kt+2, same parity).
  #define K_TILE(RBUF, SB, DOSTAGE, DOREAD, DOB, GOFF, BOFF, WAIT, BFC) do { \
    if (DOSTAGE) {                                                           \
      gld_lds16(pA0 + (GOFF), lbase + (SB) * 16384);                         \
      gld_lds16(pA1 + (GOFF), lbase + (SB) * 16384 + 8192);                  \
    }                                                                        \
    __builtin_amdgcn_sched_barrier(0);                                       \
    __builtin_amdgcn_s_setprio(1);                                           \
    _Pragma("unroll")                                                        \
    for (int m = 0; m < 4; ++m)                                              \
      _Pragma("unroll")                                                      \
      for (int n = 0; n < 4; ++n)                                            \
        acc[m][n] = __builtin_amdgcn_mfma_f32_16x16x32_bf16(                 \
            af[m], BFC[n], acc[m][n], 0, 0, 0);                              \
    __builtin_amdgcn_s_setprio(0);                                           \
    if (DOREAD) {                                                            \
      const u16* Ap_ = &smem[RBUF][wr * 128 + fr][csw];                      \
      _Pragma("unroll")                                                      \
      for (int m = 0; m < 4; ++m)                                            \
        af[m] = *(const bf16x8*)(Ap_ + m * 16 * BK);                         \
    }                                                                        \
    __builtin_amdgcn_sched_barrier(0);                                       \
    __builtin_amdgcn_s_setprio(1);                                           \
    _Pragma("unroll")                                                        \
    for (int m = 4; m < 8; ++m)                                              \
      _Pragma("unroll")                                                      \
      for (int n = 0; n < 4; ++n)                                            \
        acc[m][n] = __builtin_amdgcn_mfma_f32_16x16x32_bf16(                 \
            af[m], BFC[n], acc[m][n], 0, 0, 0);                              \
    __builtin_amdgcn_s_setprio(0);                                           \
    if (DOREAD) {                                                            \
      const u16* Ap_ = &smem[RBUF][wr * 128 + fr][csw];                      \
      _Pragma("unroll")                                                      \
      for (int m = 4; m < 8; ++m)                                            \
        af[m] = *(const bf16x8*)(Ap_ + m * 16 * BK);                         \
    }                                                                        \
    __builtin_amdgcn_sched_barrier(0);                                       \
    if (DOB) {                                                               \
      _Pragma("unroll")                                                      \
      for (int n = 0; n < 4; ++n)                                            \
        BFC[n] = *(const bf16x8*)(pB + (size_t)n * 16 * rowb + (BOFF));      \
    }                                                                        \
    __builtin_amdgcn_sched_barrier(0);                                       \
    WAIT;                                                                    \
    __builtin_amdgcn_s_barrier();                                            \
  } while (0)

  #define VM6 asm volatile("s_waitcnt vmcnt(6)" ::: "memory")
  #define VM4 asm volatile("s_waitcnt vmcnt(4)" ::: "memory")
  #define VM0 asm volatile("s_waitcnt vmcnt(0)" ::: "memory")
  #define NOW ((void)0)

  // steady: 31 groups of 4 tiles (kt = 0..123)
  for (int ktb = 0; ktb < NKT - 4; ktb += 4) {
    K_TILE(1, 3, true, true, true, 0,   0,   VM6, bfA);
    K_TILE(2, 0, true, true, true, 64,  64,  VM6, bfB);
    K_TILE(3, 1, true, true, true, 128, 128, VM6, bfA);
    K_TILE(0, 2, true, true, true, 192, 192, VM6, bfB);
    pA0 += 256; pA1 += 256; pB += 256;
  }
  // tail: kt=124 (stage S127, load B126), 125 (load B127), 126, 127
  K_TILE(1, 3, true,  true,  true,  0, 0,   VM6, bfA);
  K_TILE(2, 0, false, true,  true,  0, 64,  VM4, bfB);
  K_TILE(3, 1, false, true,  false, 0, 0,   VM0, bfA);
  K_TILE(0, 2, false, false, false, 0, 0,   NOW, bfB);

  #undef K_TILE
  #undef VM6
  #undef VM4
  #undef VM0
  #undef NOW

  // ---- epilogue: bias + masked rank-8 LoRA, fp32 out ----
  const int gn0 = bn * 256 + wc * 64;
  const size_t gm0 = (size_t)bm * 256 + wr * 128;
  float wbv[4][8]; float bv[4];
  #pragma unroll
  for (int n = 0; n < 4; ++n) {
    const int gn = gn0 + n * 16 + fr;
    bv[n] = bias[gn];
    const float4 w0 = ((const float4*)(WBw + (size_t)gn * 8))[0];
    const float4 w1 = ((const float4*)(WBw + (size_t)gn * 8))[1];
    wbv[n][0] = w0.x; wbv[n][1] = w0.y; wbv[n][2] = w0.z; wbv[n][3] = w0.w;
    wbv[n][4] = w1.x; wbv[n][5] = w1.y; wbv[n][6] = w1.z; wbv[n][7] = w1.w;
  }
  #pragma unroll
  for (int m = 0; m < 8; ++m) {
    #pragma unroll
    for (int j = 0; j < 4; ++j) {
      const size_t gm = gm0 + m * 16 + fq * 4 + j;   // C/D row = (l>>4)*4+reg
      const int msk = mask[gm];
      const float4 m0 = ((const float4*)(mid + gm * 8))[0];
      const float4 m1 = ((const float4*)(mid + gm * 8))[1];
      float* orow = out + gm * (size_t)N_DIM;
      #pragma unroll
      for (int n = 0; n < 4; ++n) {
        const float lora =
            m0.x * wbv[n][0] + m0.y * wbv[n][1] + m0.z * wbv[n][2] + m0.w * wbv[n][3] +
            m1.x * wbv[n][4] + m1.y * wbv[n][5] + m1.z * wbv[n][6] + m1.w * wbv[n][7];
        orow[gn0 + n * 16 + fr] = acc[m][n][j] + bv[n] + (msk ? lora : 0.0f);
      }
    }
  }
}

extern "C" void kernel_launch(void* const* d_in, const int* in_sizes, int n_in,
                              void* d_out, int out_size, void* d_ws, size_t ws_size,
                              hipStream_t stream) {
  (void)in_sizes; (void)n_in; (void)out_size; (void)ws_size;
  const float* x     = (const float*)d_in[0];
  const int*   mask  = (const int*)d_in[1];
  const float* Wm    = (const float*)d_in[2];
  const float* bmain = (const float*)d_in[3];
  const float* WA    = (const float*)d_in[4];
  const float* WB    = (const float*)d_in[5];
  float* out = (float*)d_out;

  u16* xb  = (u16*)d_ws;                                // 64 MiB
  u16* wb  = xb + (size_t)M_TOK * K_DIM;                // 32 MiB
  float* mid = (float*)(wb + (size_t)N_DIM * K_DIM);    // 256 KiB

  k_prep<<<M_TOK + 2048, 256, 0, stream>>>(x, WA, Wm, xb, mid, wb);
  dim3 grid((M_TOK / 256) * (N_DIM / 256));             // 512 blocks
  k_gemm<<<grid, 512, 0, stream>>>(xb, wb, bmain, mask, mid, WB, out);
}

// Round 15
// 359.838 us; speedup vs baseline: 1.2731x; 1.2731x over previous
//
#include <hip/hip_runtime.h>

typedef unsigned short u16;
typedef unsigned int   u32;
typedef unsigned long long u64;
typedef __bf16 bf16x8 __attribute__((ext_vector_type(8)));
typedef float  f32x4  __attribute__((ext_vector_type(4)));

#define AS1 __attribute__((address_space(1)))
#define AS3 __attribute__((address_space(3)))

#define M_TOK 8192
#define K_DIM 4096
#define N_DIM 4096
#define BK    32
#define NKT   (K_DIM / BK)   // 128

static __device__ __forceinline__ u16 f2bf(float f) {
  u32 u = __builtin_bit_cast(u32, f);
  return (u16)((u + (0x7FFFu + ((u >> 16) & 1u))) >> 16);
}

// global -> LDS direct copy, 16B per lane. LDS dest is wave-uniform base;
// HW stores lane l at dest + l*16 (linear, rule #21).
static __device__ __forceinline__ void gld_lds16(const void* g, void* l) {
  __builtin_amdgcn_global_load_lds((AS1 u32*)(u64)g, (AS3 u32*)(u32)(u64)l, 16, 0, 0);
}

// ---- fused prep: blocks [0, M_TOK) do per-token x->bf16 + LoRA mid;
//      blocks [M_TOK, M_TOK+2048) convert W_main f32->bf16 (grid-stride). ----
__global__ __launch_bounds__(256) void k_prep(const float* __restrict__ x,
                                              const float* __restrict__ WA,
                                              const float* __restrict__ W,
                                              u16* __restrict__ xb,
                                              float* __restrict__ mid,
                                              u16* __restrict__ Wb) {
  const int t = threadIdx.x;
  if (blockIdx.x >= M_TOK) {
    const int cb = blockIdx.x - M_TOK;           // 0..2047
    const float4* W4 = (const float4*)W;
    ushort4* Wb4 = (ushort4*)Wb;
    const int n4 = (N_DIM * K_DIM) / 4;
    int i = cb * 256 + t;
    for (; i < n4; i += 2048 * 256) {
      float4 v = W4[i];
      ushort4 o;
      o.x = f2bf(v.x); o.y = f2bf(v.y); o.z = f2bf(v.z); o.w = f2bf(v.w);
      Wb4[i] = o;
    }
    return;
  }
  const int m = blockIdx.x;
  const float4* xr = (const float4*)(x + (size_t)m * K_DIM);
  ushort4* xbr = (ushort4*)(xb + (size_t)m * K_DIM);
  float a[8] = {0.f,0.f,0.f,0.f,0.f,0.f,0.f,0.f};
  #pragma unroll
  for (int i = 0; i < 4; ++i) {
    const int k4 = t + i * 256;
    float4 v = xr[k4];
    ushort4 o;
    o.x = f2bf(v.x); o.y = f2bf(v.y); o.z = f2bf(v.z); o.w = f2bf(v.w);
    xbr[k4] = o;
    #pragma unroll
    for (int r = 0; r < 8; ++r) {
      float4 wv = ((const float4*)(WA + (size_t)r * K_DIM))[k4];
      a[r] += v.x * wv.x + v.y * wv.y + v.z * wv.z + v.w * wv.w;
    }
  }
  #pragma unroll
  for (int r = 0; r < 8; ++r) {
    #pragma unroll
    for (int off = 32; off > 0; off >>= 1)
      a[r] += __shfl_down(a[r], off);
  }
  __shared__ float red[4][8];
  const int w = t >> 6, l = t & 63;
  if (l == 0) {
    #pragma unroll
    for (int r = 0; r < 8; ++r) red[w][r] = a[r];
  }
  __syncthreads();
  if (t < 8)
    mid[(size_t)m * 8 + t] = 2.0f * (red[0][t] + red[1][t] + red[2][t] + red[3][t]);
}

// ---- main GEMM: 256x128 tile, BK=32, 4 waves (2Mx2N), 256 threads,
// ring-3 LDS (72 KiB) -> TWO INDEPENDENT BLOCKS PER CU.
// R15: same total waves/CU (8 = 2/SIMD, register-legal: 256 regs/wave),
//   but split across two blocks with INDEPENDENT barriers.  Six one-block
//   schedules all measured tile = MFMA(1242) + LDS(~1230) SUMMED because
//   every resident wave hits the same barrier: CU-wide read-burst then
//   CU-wide MFMA-burst.  Two blocks drift into antiphase -> one block's
//   MFMA covers the other's LDS burst (m114).  R11's attempt failed
//   because 2 x 512-thr blocks can't fit the register file; 2 x 256-thr
//   blocks fit exactly (LDS 2x72=144<=160, VGPR 2/SIMD).
//
// Per-wave body = R5's proven 124-VGPR one (acc[8][4], 12 ds_read/tile,
// 32 MFMA).  Staging per tile: A 16KB = 4 gld_lds + B 8KB = 2 (per-wave
// 1KB each, dest wid*1024).  Ring-3, counted vmcnt:
//   tile kt: stage s(kt+2) -> buf[(kt+2)%3] (= buf[kt-1], reads drained
//   before MFMA(kt-1) -> one barrier ago -> safe); 12 ds_read frags(kt);
//   32 MFMA; vmcnt(6) retires s(kt+1); barrier.
//   Prologue: stage t0,t1 (12 ops), vmcnt(6) retires t0, barrier.
//   Steady: 42 groups of 3 (kt 0..125, literal bufs 0,1,2; stage GOFF
//   0/64/128 from pointers pre-offset to tile 2, +192/group).
//   Tail: kt=126 (buf0, no stage, vmcnt(0) retires s127), kt=127 (buf1).
__global__ __launch_bounds__(256, 2) void k_gemm(
    const u16* __restrict__ A, const u16* __restrict__ B,
    const float* __restrict__ bias, const int* __restrict__ mask,
    const float* __restrict__ mid, const float* __restrict__ WBw,
    float* __restrict__ out) {
  __shared__ u16 smem[3][12288];   // 3 bufs x 24KB (A 16KB + B 8KB) = 72 KiB
  char* lds = (char*)&smem[0][0];

  const int t = threadIdx.x;
  const int wid = t >> 6, l = t & 63;
  const int wr = wid >> 1, wc = wid & 1;   // 2x2 wave grid -> 128x64 out/wave
  const int fr = l & 15, fq = l >> 4;

  // T1: XCD-aware swizzle (1024 blocks, 1024%8==0 -> bijective)
  const int bid = blockIdx.x;
  const int swz = (bid & 7) * 128 + (bid >> 3);
  const int bm = swz >> 5, bn = swz & 31;   // 32 x 32 tile grid

  const char* Ag = (const char*)(A + (size_t)bm * 256 * K_DIM);
  const char* Bg = (const char*)(B + (size_t)bn * 128 * K_DIM);
  const size_t rowb = (size_t)K_DIM * 2;

  // staging: 256 thr x 16B = 4KB per gld_lds statement (1KB per wave).
  // thread t covers row (t>>2) of each 64-row group; source 16B chunk is
  // the pre-swizzle (t&3)^((t>>3)&3); row stride in LDS = 64B.
  const int srow = t >> 2;
  const int schk = (((t & 3) ^ ((t >> 3) & 3)) * 16);
  const char* sA0 = Ag + (size_t)(  0 + srow) * rowb + schk;
  const char* sA1 = Ag + (size_t)( 64 + srow) * rowb + schk;
  const char* sA2 = Ag + (size_t)(128 + srow) * rowb + schk;
  const char* sA3 = Ag + (size_t)(192 + srow) * rowb + schk;
  const char* sB0 = Bg + (size_t)(  0 + srow) * rowb + schk;
  const char* sB1 = Bg + (size_t)( 64 + srow) * rowb + schk;
  const int widoff = wid * 1024;

  f32x4 acc[8][4];
  #pragma unroll
  for (int m = 0; m < 8; ++m)
    #pragma unroll
    for (int n = 0; n < 4; ++n)
      acc[m][n] = (f32x4){0.f, 0.f, 0.f, 0.f};

  // stage tile TT (6 statements) into buf BUFV at tile byte-offset GOFF
  #define STAGE6(BUFV, GOFF) do {                                            \
    char* b_ = lds + (BUFV) * 24576 + widoff;                                \
    gld_lds16(sA0 + (GOFF), b_);                                             \
    gld_lds16(sA1 + (GOFF), b_ + 4096);                                      \
    gld_lds16(sA2 + (GOFF), b_ + 8192);                                      \
    gld_lds16(sA3 + (GOFF), b_ + 12288);                                     \
    gld_lds16(sB0 + (GOFF), b_ + 16384);                                     \
    gld_lds16(sB1 + (GOFF), b_ + 20480);                                     \
  } while (0)

  // prologue: tiles 0,1 -> bufs 0,1; vmcnt(6) retires tile 0
  STAGE6(0, 0);
  STAGE6(1, 64);
  asm volatile("s_waitcnt vmcnt(6)" ::: "memory");
  __builtin_amdgcn_s_barrier();

  // read-side swizzled column (u16 units), wave-invariant
  const int csw = (fq ^ ((fr >> 1) & 3)) * 8;

  // running stage pointers, pre-offset to tile 2 (= kt+2 at kt=0)
  const char* base = (const char*)0;   // (unused sentinel)
  (void)base;
  #define ADV(P) P += 192
  const char* pA0 = sA0 + 128; const char* pA1 = sA1 + 128;
  const char* pA2 = sA2 + 128; const char* pA3 = sA3 + 128;
  const char* pB0 = sB0 + 128; const char* pB1 = sB1 + 128;

  #define STAGE6P(BUFV, GOFF) do {                                           \
    char* b_ = lds + (BUFV) * 24576 + widoff;                                \
    gld_lds16(pA0 + (GOFF), b_);                                             \
    gld_lds16(pA1 + (GOFF), b_ + 4096);                                      \
    gld_lds16(pA2 + (GOFF), b_ + 8192);                                      \
    gld_lds16(pA3 + (GOFF), b_ + 12288);                                     \
    gld_lds16(pB0 + (GOFF), b_ + 16384);                                     \
    gld_lds16(pB1 + (GOFF), b_ + 20480);                                     \
  } while (0)

  // One K32-tile: stage(kt+2) -> 12 frag reads -> 32 MFMA -> wait -> barrier
  #define K_TILE(BUFC, NB, DOSTAGE, GOFF, WAIT) do {                         \
    if (DOSTAGE) STAGE6P(NB, GOFF);                                          \
    {                                                                        \
      const u16* Ab_ = (const u16*)(lds + (BUFC) * 24576)                    \
                       + (wr * 128 + fr) * 32 + csw;                         \
      const u16* Bb_ = (const u16*)(lds + (BUFC) * 24576 + 16384)            \
                       + (wc * 64 + fr) * 32 + csw;                          \
      bf16x8 af_[8], bf_[4];                                                 \
      _Pragma("unroll")                                                      \
      for (int m = 0; m < 8; ++m)                                            \
        af_[m] = *(const bf16x8*)(Ab_ + m * 16 * 32);                        \
      _Pragma("unroll")                                                      \
      for (int n = 0; n < 4; ++n)                                            \
        bf_[n] = *(const bf16x8*)(Bb_ + n * 16 * 32);                        \
      __builtin_amdgcn_s_setprio(1);                                         \
      _Pragma("unroll")                                                      \
      for (int m = 0; m < 8; ++m)                                            \
        _Pragma("unroll")                                                    \
        for (int n = 0; n < 4; ++n)                                          \
          acc[m][n] = __builtin_amdgcn_mfma_f32_16x16x32_bf16(               \
              af_[m], bf_[n], acc[m][n], 0, 0, 0);                           \
      __builtin_amdgcn_s_setprio(0);                                         \
    }                                                                        \
    WAIT;                                                                    \
    __builtin_amdgcn_s_barrier();                                            \
  } while (0)

  #define VM6 asm volatile("s_waitcnt vmcnt(6)" ::: "memory")
  #define VM0 asm volatile("s_waitcnt vmcnt(0)" ::: "memory")
  #define NOW ((void)0)

  // steady: 42 groups of 3 tiles (kt = 0..125), stage kt+2, vmcnt(6)
  for (int g = 0; g < 42; ++g) {
    K_TILE(0, 2, true, 0,   VM6);
    K_TILE(1, 0, true, 64,  VM6);
    K_TILE(2, 1, true, 128, VM6);
    ADV(pA0); ADV(pA1); ADV(pA2); ADV(pA3); ADV(pB0); ADV(pB1);
  }
  // tail: kt=126 (buf0, no stage, drain s127), kt=127 (buf1)
  K_TILE(0, 2, false, 0, VM0);
  K_TILE(1, 0, false, 0, NOW);

  #undef K_TILE
  #undef STAGE6P
  #undef STAGE6
  #undef ADV
  #undef VM6
  #undef VM0
  #undef NOW

  // ---- epilogue: bias + masked rank-8 LoRA, fp32 out ----
  const int gn0 = bn * 128 + wc * 64;
  const size_t gm0 = (size_t)bm * 256 + wr * 128;
  float wbv[4][8]; float bv[4];
  #pragma unroll
  for (int n = 0; n < 4; ++n) {
    const int gn = gn0 + n * 16 + fr;
    bv[n] = bias[gn];
    const float4 w0 = ((const float4*)(WBw + (size_t)gn * 8))[0];
    const float4 w1 = ((const float4*)(WBw + (size_t)gn * 8))[1];
    wbv[n][0] = w0.x; wbv[n][1] = w0.y; wbv[n][2] = w0.z; wbv[n][3] = w0.w;
    wbv[n][4] = w1.x; wbv[n][5] = w1.y; wbv[n][6] = w1.z; wbv[n][7] = w1.w;
  }
  #pragma unroll
  for (int m = 0; m < 8; ++m) {
    #pragma unroll
    for (int j = 0; j < 4; ++j) {
      const size_t gm = gm0 + m * 16 + fq * 4 + j;   // C/D row = (l>>4)*4+reg
      const int msk = mask[gm];
      const float4 m0 = ((const float4*)(mid + gm * 8))[0];
      const float4 m1 = ((const float4*)(mid + gm * 8))[1];
      float* orow = out + gm * (size_t)N_DIM;
      #pragma unroll
      for (int n = 0; n < 4; ++n) {
        const float lora =
            m0.x * wbv[n][0] + m0.y * wbv[n][1] + m0.z * wbv[n][2] + m0.w * wbv[n][3] +
            m1.x * wbv[n][4] + m1.y * wbv[n][5] + m1.z * wbv[n][6] + m1.w * wbv[n][7];
        orow[gn0 + n * 16 + fr] = acc[m][n][j] + bv[n] + (msk ? lora : 0.0f);
      }
    }
  }
}

extern "C" void kernel_launch(void* const* d_in, const int* in_sizes, int n_in,
                              void* d_out, int out_size, void* d_ws, size_t ws_size,
                              hipStream_t stream) {
  (void)in_sizes; (void)n_in; (void)out_size; (void)ws_size;
  const float* x     = (const float*)d_in[0];
  const int*   mask  = (const int*)d_in[1];
  const float* Wm    = (const float*)d_in[2];
  const float* bmain = (const float*)d_in[3];
  const float* WA    = (const float*)d_in[4];
  const float* WB    = (const float*)d_in[5];
  float* out = (float*)d_out;

  u16* xb  = (u16*)d_ws;                                // 64 MiB
  u16* wb  = xb + (size_t)M_TOK * K_DIM;                // 32 MiB
  float* mid = (float*)(wb + (size_t)N_DIM * K_DIM);    // 256 KiB

  k_prep<<<M_TOK + 2048, 256, 0, stream>>>(x, WA, Wm, xb, mid, wb);
  dim3 grid((M_TOK / 256) * (N_DIM / 128));             // 1024 blocks
  k_gemm<<<grid, 256, 0, stream>>>(xb, wb, bmain, mask, mid, WB, out);
}

// Round 16
// 322.150 us; speedup vs baseline: 1.4221x; 1.1170x over previous
//
#include <hip/hip_runtime.h>

typedef unsigned short u16;
typedef unsigned int   u32;
typedef unsigned long long u64;
typedef __bf16 bf16x8 __attribute__((ext_vector_type(8)));
typedef float  f32x4  __attribute__((ext_vector_type(4)));

#define AS1 __attribute__((address_space(1)))
#define AS3 __attribute__((address_space(3)))

#define M_TOK 8192
#define K_DIM 4096
#define N_DIM 4096
#define BK    64
#define NKT   (K_DIM / BK)   // 64

static __device__ __forceinline__ u16 f2bf(float f) {
  u32 u = __builtin_bit_cast(u32, f);
  return (u16)((u + (0x7FFFu + ((u >> 16) & 1u))) >> 16);
}

// global -> LDS direct copy, 16B per lane. LDS dest is wave-uniform base;
// HW stores lane l at dest + l*16 (linear, rule #21).
static __device__ __forceinline__ void gld_lds16(const void* g, void* l) {
  __builtin_amdgcn_global_load_lds((AS1 u32*)(u64)g, (AS3 u32*)(u32)(u64)l, 16, 0, 0);
}

// ---- fused prep: blocks [0, M_TOK) do per-token x->bf16 + LoRA mid;
//      blocks [M_TOK, M_TOK+2048) convert W_main f32->bf16 (grid-stride). ----
__global__ __launch_bounds__(256) void k_prep(const float* __restrict__ x,
                                              const float* __restrict__ WA,
                                              const float* __restrict__ W,
                                              u16* __restrict__ xb,
                                              float* __restrict__ mid,
                                              u16* __restrict__ Wb) {
  const int t = threadIdx.x;
  if (blockIdx.x >= M_TOK) {
    const int cb = blockIdx.x - M_TOK;           // 0..2047
    const float4* W4 = (const float4*)W;
    ushort4* Wb4 = (ushort4*)Wb;
    const int n4 = (N_DIM * K_DIM) / 4;
    int i = cb * 256 + t;
    for (; i < n4; i += 2048 * 256) {
      float4 v = W4[i];
      ushort4 o;
      o.x = f2bf(v.x); o.y = f2bf(v.y); o.z = f2bf(v.z); o.w = f2bf(v.w);
      Wb4[i] = o;
    }
    return;
  }
  const int m = blockIdx.x;
  const float4* xr = (const float4*)(x + (size_t)m * K_DIM);
  ushort4* xbr = (ushort4*)(xb + (size_t)m * K_DIM);
  float a[8] = {0.f,0.f,0.f,0.f,0.f,0.f,0.f,0.f};
  #pragma unroll
  for (int i = 0; i < 4; ++i) {
    const int k4 = t + i * 256;
    float4 v = xr[k4];
    ushort4 o;
    o.x = f2bf(v.x); o.y = f2bf(v.y); o.z = f2bf(v.z); o.w = f2bf(v.w);
    xbr[k4] = o;
    #pragma unroll
    for (int r = 0; r < 8; ++r) {
      float4 wv = ((const float4*)(WA + (size_t)r * K_DIM))[k4];
      a[r] += v.x * wv.x + v.y * wv.y + v.z * wv.z + v.w * wv.w;
    }
  }
  #pragma unroll
  for (int r = 0; r < 8; ++r) {
    #pragma unroll
    for (int off = 32; off > 0; off >>= 1)
      a[r] += __shfl_down(a[r], off);
  }
  __shared__ float red[4][8];
  const int w = t >> 6, l = t & 63;
  if (l == 0) {
    #pragma unroll
    for (int r = 0; r < 8; ++r) red[w][r] = a[r];
  }
  __syncthreads();
  if (t < 8)
    mid[(size_t)m * 8 + t] = 2.0f * (red[0][t] + red[1][t] + red[2][t] + red[3][t]);
}

// ---- main GEMM: 256x256 tile, BK=64, 8 waves (2Mx4N), 2-dbuf (128 KiB).
// R16 = R12 with two fixes toward the m201 template:
//  (1) BALANCED PHASES: phase = (m-half h, K32-half ks); reads per phase
//      {8,4,8,4} (A 4 frags always; B 4 frags only when ks changes) vs
//      R12's {12,4,4,4} spike (all-B upfront = 768-cyc CU drain at P0).
//  (2) NEVER DRAIN BELOW 2 IN FLIGHT, waits placed where the data is
//      needed: VM2 at P0-end (retires carry = A G1,G3 of THIS tile,
//      needed by P1) and VM2 at P3-end (retires B G0-3 + A G0,G2 of
//      tile kt+1, needed by kt+1 P0).
//
// Phase reads (wave (wr,wc), frag rows wr*128 + (4h+i)*16 + fr):
//   P0 (h0,ks0): A G0(wr0)/G2(wr1) + B all;  P1 (h1,ks0): A G1/G3;
//   P2 (h0,ks1): A G0/G2 + B all;            P3 (h1,ks1): A G1/G3.
// Stage order during kt (2 gld_lds/phase, tile kt+1 -> buf (kt+1)&1,
// whose content (tile kt-1) was fully read by end of kt-1 -> safe):
//   P0: B G0,G1   P1: B G2,G3   P2: A G0,G2   P3: A G1,G3.
// FIFO ledger (8 loads/tile/wave): carry into kt = 2 (kt-1 P3's A G1,G3
// of tile kt).  P0-end: outstanding 4 -> VM2 retires carry (P1 safe).
// P3-end: outstanding 10 -> VM2 retires 8 = B+A02 of kt+1 (kt+1 P0 safe),
// leaves P3's pair.  Prologue: stage tile 0 fully, VM0 (tile0 P0's VM2 is
// then a no-op).  Tail: tile 63 P0-end VM0 (retires tile-62 P3 pair),
// P3-end none.
__global__ __launch_bounds__(512, 2) void k_gemm(
    const u16* __restrict__ A, const u16* __restrict__ B,
    const float* __restrict__ bias, const int* __restrict__ mask,
    const float* __restrict__ mid, const float* __restrict__ WBw,
    float* __restrict__ out) {
  __shared__ u16 smem[2][2][256][64];   // 128 KiB
  char* lds = (char*)&smem[0][0][0][0];

  const int t = threadIdx.x;
  const int wid = t >> 6, l = t & 63;
  const int wr = wid >> 2, wc = wid & 3;   // 2x4 wave grid -> 128x64 out/wave
  const int fr = l & 15, fq = l >> 4;

  // T1: XCD-aware swizzle (512 blocks, 512%8==0 -> bijective)
  const int bid = blockIdx.x;
  const int swz = (bid & 7) * 64 + (bid >> 3);
  const int bm = swz >> 4, bn = swz & 15;

  const char* Ag = (const char*)(A + (size_t)bm * 256 * K_DIM);
  const char* Bg = (const char*)(B + (size_t)bn * 256 * K_DIM);
  const size_t rowb = (size_t)K_DIM * 2;   // 8192 B

  // staging: thread t covers row-in-group t>>3, source 16B chunk
  // (t&7)^((t>>3)&7) of the 128B row segment (coalesced per 8-lane group).
  const int srow8 = t >> 3;
  const int schk = (((t & 7) ^ ((t >> 3) & 7)) * 16);
  const char* sA0 = Ag + (size_t)(  0 + srow8) * rowb + schk;
  const char* sA1 = Ag + (size_t)( 64 + srow8) * rowb + schk;
  const char* sA2 = Ag + (size_t)(128 + srow8) * rowb + schk;
  const char* sA3 = Ag + (size_t)(192 + srow8) * rowb + schk;
  const char* sB0 = Bg + (size_t)(  0 + srow8) * rowb + schk;
  const char* sB1 = Bg + (size_t)( 64 + srow8) * rowb + schk;
  const char* sB2 = Bg + (size_t)(128 + srow8) * rowb + schk;
  const char* sB3 = Bg + (size_t)(192 + srow8) * rowb + schk;
  const int widoff = wid * 1024;

  // read-side: swizzled slot offsets (slot s holds chunk s^(row&7);
  // frag row&7 == fr&7, wave-invariant) and frag bases
  const int so0 = ((0 + fq) ^ (fr & 7)) * 16;
  const int so1 = ((4 + fq) ^ (fr & 7)) * 16;
  const int aoff = (wr * 128 + fr) * 128;            // within A half
  const int boff = 32768 + (wc * 64 + fr) * 128;     // within buffer

  f32x4 acc[8][4];
  #pragma unroll
  for (int m = 0; m < 8; ++m)
    #pragma unroll
    for (int n = 0; n < 4; ++n)
      acc[m][n] = (f32x4){0.f, 0.f, 0.f, 0.f};

  // prologue: stage tile 0 -> buf0 (all 8 groups, read-need order), drain
  gld_lds16(sB0, lds + 32768 +     0 + widoff);
  gld_lds16(sB1, lds + 32768 +  8192 + widoff);
  gld_lds16(sB2, lds + 32768 + 16384 + widoff);
  gld_lds16(sB3, lds + 32768 + 24576 + widoff);
  gld_lds16(sA0, lds +     0 + widoff);
  gld_lds16(sA2, lds + 16384 + widoff);
  gld_lds16(sA1, lds +  8192 + widoff);
  gld_lds16(sA3, lds + 24576 + widoff);
  asm volatile("s_waitcnt vmcnt(0)" ::: "memory");
  __builtin_amdgcn_s_barrier();

  bf16x8 bq[4];   // B frags of the current ks (4), reloaded at P0/P2

  #define VM2 asm volatile("s_waitcnt vmcnt(2)" ::: "memory")
  #define VM0 asm volatile("s_waitcnt vmcnt(0)" ::: "memory")
  #define NOW ((void)0)

  // Phase (H = m-half, KS = K32-half) of the tile in buffer BUF.
  #define PHASE(BUF, H, KS, LOADB, DOSTAGE, S0, S1, D0, D1, GOFF, WAIT) do { \
    const char* Ab_ = lds + (BUF) * 65536 + aoff;                            \
    const int so_ = (KS) ? so1 : so0;                                        \
    bf16x8 a0_ = *(const bf16x8*)(Ab_ + (4*(H)+0) * 2048 + so_);             \
    bf16x8 a1_ = *(const bf16x8*)(Ab_ + (4*(H)+1) * 2048 + so_);             \
    bf16x8 a2_ = *(const bf16x8*)(Ab_ + (4*(H)+2) * 2048 + so_);             \
    bf16x8 a3_ = *(const bf16x8*)(Ab_ + (4*(H)+3) * 2048 + so_);             \
    if (LOADB) {                                                             \
      const char* Bb_ = lds + (BUF) * 65536 + boff;                          \
      _Pragma("unroll")                                                      \
      for (int n = 0; n < 4; ++n)                                            \
        bq[n] = *(const bf16x8*)(Bb_ + n * 2048 + so_);                      \
    }                                                                        \
    if (DOSTAGE) {                                                           \
      gld_lds16((S0) + (GOFF), lds + ((BUF)^1) * 65536 + (D0) + widoff);     \
      gld_lds16((S1) + (GOFF), lds + ((BUF)^1) * 65536 + (D1) + widoff);     \
    }                                                                        \
    __builtin_amdgcn_sched_barrier(0);                                       \
    __builtin_amdgcn_s_barrier();                                            \
    __builtin_amdgcn_s_setprio(1);                                           \
    _Pragma("unroll")                                                        \
    for (int n = 0; n < 4; ++n) {                                            \
      acc[4*(H)+0][n] = __builtin_amdgcn_mfma_f32_16x16x32_bf16(             \
          a0_, bq[n], acc[4*(H)+0][n], 0, 0, 0);                             \
      acc[4*(H)+1][n] = __builtin_amdgcn_mfma_f32_16x16x32_bf16(             \
          a1_, bq[n], acc[4*(H)+1][n], 0, 0, 0);                             \
      acc[4*(H)+2][n] = __builtin_amdgcn_mfma_f32_16x16x32_bf16(             \
          a2_, bq[n], acc[4*(H)+2][n], 0, 0, 0);                             \
      acc[4*(H)+3][n] = __builtin_amdgcn_mfma_f32_16x16x32_bf16(             \
          a3_, bq[n], acc[4*(H)+3][n], 0, 0, 0);                             \
    }                                                                        \
    __builtin_amdgcn_s_setprio(0);                                           \
    WAIT;                                                                    \
    __builtin_amdgcn_s_barrier();                                            \
  } while (0)

  // one K64-tile: phases (h0,ks0),(h1,ks0),(h0,ks1),(h1,ks1); stage order
  // {B01, B23, A02, A13}; waits W0 at P0-end, W3 at P3-end.
  #define K_TILE(BUF, DOSTAGE, GOFF, W0, W3)                                 \
    PHASE(BUF, 0, 0, true,  DOSTAGE, sB0, sB1, 32768+0,     32768+8192,  GOFF, W0);  \
    PHASE(BUF, 1, 0, false, DOSTAGE, sB2, sB3, 32768+16384, 32768+24576, GOFF, NOW); \
    PHASE(BUF, 0, 1, true,  DOSTAGE, sA0, sA2, 0,           16384,       GOFF, NOW); \
    PHASE(BUF, 1, 1, false, DOSTAGE, sA1, sA3, 8192,        24576,       GOFF, W3)

  // steady: 31 iters x 2 tiles (tiles 0..61)
  for (int it = 0; it < 31; ++it) {
    K_TILE(0, true, 128, VM2, VM2);
    K_TILE(1, true, 256, VM2, VM2);
    sA0 += 256; sA1 += 256; sA2 += 256; sA3 += 256;
    sB0 += 256; sB1 += 256; sB2 += 256; sB3 += 256;
  }
  // tile 62 (buf0): stages tile 63 (GOFF 128)
  K_TILE(0, true, 128, VM2, VM2);
  // tile 63 (buf1): no staging; P0-end VM0 retires tile-62-P3's pair
  K_TILE(1, false, 0, VM0, NOW);

  #undef K_TILE
  #undef PHASE
  #undef VM2
  #undef VM0
  #undef NOW

  // ---- epilogue: bias + masked rank-8 LoRA, fp32 out ----
  const int gn0 = bn * 256 + wc * 64;
  const size_t gm0 = (size_t)bm * 256 + wr * 128;
  float wbv[4][8]; float bv[4];
  #pragma unroll
  for (int n = 0; n < 4; ++n) {
    const int gn = gn0 + n * 16 + fr;
    bv[n] = bias[gn];
    const float4 w0 = ((const float4*)(WBw + (size_t)gn * 8))[0];
    const float4 w1 = ((const float4*)(WBw + (size_t)gn * 8))[1];
    wbv[n][0] = w0.x; wbv[n][1] = w0.y; wbv[n][2] = w0.z; wbv[n][3] = w0.w;
    wbv[n][4] = w1.x; wbv[n][5] = w1.y; wbv[n][6] = w1.z; wbv[n][7] = w1.w;
  }
  #pragma unroll
  for (int m = 0; m < 8; ++m) {
    #pragma unroll
    for (int j = 0; j < 4; ++j) {
      const size_t gm = gm0 + m * 16 + fq * 4 + j;   // C/D row = (l>>4)*4+reg
      const int msk = mask[gm];
      const float4 m0 = ((const float4*)(mid + gm * 8))[0];
      const float4 m1 = ((const float4*)(mid + gm * 8))[1];
      float* orow = out + gm * (size_t)N_DIM;
      #pragma unroll
      for (int n = 0; n < 4; ++n) {
        const float lora =
            m0.x * wbv[n][0] + m0.y * wbv[n][1] + m0.z * wbv[n][2] + m0.w * wbv[n][3] +
            m1.x * wbv[n][4] + m1.y * wbv[n][5] + m1.z * wbv[n][6] + m1.w * wbv[n][7];
        orow[gn0 + n * 16 + fr] = acc[m][n][j] + bv[n] + (msk ? lora : 0.0f);
      }
    }
  }
}

extern "C" void kernel_launch(void* const* d_in, const int* in_sizes, int n_in,
                              void* d_out, int out_size, void* d_ws, size_t ws_size,
                              hipStream_t stream) {
  (void)in_sizes; (void)n_in; (void)out_size; (void)ws_size;
  const float* x     = (const float*)d_in[0];
  const int*   mask  = (const int*)d_in[1];
  const float* Wm    = (const float*)d_in[2];
  const float* bmain = (const float*)d_in[3];
  const float* WA    = (const float*)d_in[4];
  const float* WB    = (const float*)d_in[5];
  float* out = (float*)d_out;

  u16* xb  = (u16*)d_ws;                                // 64 MiB
  u16* wb  = xb + (size_t)M_TOK * K_DIM;                // 32 MiB
  float* mid = (float*)(wb + (size_t)N_DIM * K_DIM);    // 256 KiB

  k_prep<<<M_TOK + 2048, 256, 0, stream>>>(x, WA, Wm, xb, mid, wb);
  dim3 grid((M_TOK / 256) * (N_DIM / 256));             // 512 blocks
  k_gemm<<<grid, 512, 0, stream>>>(xb, wb, bmain, mask, mid, WB, out);
}